// Round 6
// baseline (786.202 us; speedup 1.0000x reference)
//
#include <hip/hip_runtime.h>
#include <hip/hip_bf16.h>

typedef __attribute__((ext_vector_type(8))) short short8;
typedef __attribute__((ext_vector_type(4))) float f32x4;

constexpr int S_DIM   = 1024;
constexpr int IN_DIM  = 4096;   // K
constexpr int OUT_DIM = 4096;   // N
constexpr int NLORA   = 8;

typedef __attribute__((address_space(3))) unsigned char lds_byte_t;
typedef const __attribute__((address_space(1))) unsigned char glb_byte_t;

__device__ __forceinline__ unsigned short f2bf(float a) {
    union { __hip_bfloat16 h; unsigned short u; } c;
    c.h = __float2bfloat16(a);
    return c.u;
}
__device__ __forceinline__ unsigned int bf2pk(float a, float b) {
    return (unsigned int)f2bf(a) | ((unsigned int)f2bf(b) << 16);
}

// ---- prep: x fp32 -> bf16 ---------------------------------------------------
__global__ __launch_bounds__(256)
void prep_x(const float* __restrict__ x, unsigned short* __restrict__ xb, int n8) {
    const int stride = gridDim.x * blockDim.x;
    for (int i = blockIdx.x * blockDim.x + threadIdx.x; i < n8; i += stride) {
        const size_t o = (size_t)i * 8;
        f32x4 v0 = *reinterpret_cast<const f32x4*>(x + o);
        f32x4 v1 = *reinterpret_cast<const f32x4*>(x + o + 4);
        uint4 d;
        d.x = bf2pk(v0[0], v0[1]);
        d.y = bf2pk(v0[2], v0[3]);
        d.z = bf2pk(v1[0], v1[1]);
        d.w = bf2pk(v1[2], v1[3]);
        *reinterpret_cast<uint4*>(xb + o) = d;
    }
}

// ---- main GEMM: A via LDS (proven path), B direct from fp32 w[k][n] ---------
constexpr int BM = 256;
constexpr int BN = 256;
constexpr int BK = 64;
constexpr int NT = IN_DIM / BK;   // 64

__global__ __launch_bounds__(512, 2)
void gemm_f(const unsigned short* __restrict__ xb, const float* __restrict__ w,
            const int* __restrict__ aids, float* __restrict__ out) {
    __shared__ __align__(16) unsigned char As[2][32768];   // A only: 64 KiB

    // T1 XCD swizzle: 512 wgs, 64/XCD = one batch per XCD
    const int bid = blockIdx.x;
    const int swz = (bid & 7) * 64 + (bid >> 3);
    const int bz  = swz >> 6;
    const int rem = swz & 63;
    const int by  = rem >> 4;
    const int bx  = rem & 15;

    const int tid  = threadIdx.x;
    const int lane = tid & 63;
    const int wid  = tid >> 6;
    const int bm0  = by * BM;
    const int bn0  = bx * BN;
    const int aid  = aids[bz];

    const unsigned short* Ab = xb + ((size_t)bz * S_DIM + bm0) * IN_DIM;
    const float* Wb = w + (size_t)aid * IN_DIM * OUT_DIM + bn0;

    const int wr  = (wid >> 2) * 128;
    const int wc  = (wid & 3) * 64;
    const int l15 = lane & 15;
    const int lk  = lane >> 4;

    // A staging (verified rounds 3-5): chunk = 8 rows x 128B, linear LDS dest,
    // source k pre-swizzled so ds_read with byte ^ ((row&7)<<4) is conflict-free.
    const int rl   = lane >> 3;
    const int ksrc = ((lane & 7) ^ rl) << 3;

    f32x4 acc[8][4] = {};

    auto stageA = [&](int buf, int k0, int h) {
        #pragma unroll
        for (int c = 0; c < 2; ++c) {
            const int chunk = h * 16 + wid * 2 + c;
            const int row   = chunk * 8 + rl;
            __builtin_amdgcn_global_load_lds(
                (glb_byte_t*)(Ab + (size_t)row * IN_DIM + k0 + ksrc),
                (lds_byte_t*)(&As[buf][chunk * 1024]), 16, 0, 0);
        }
    };
    auto readA = [&](int buf, int mh, short8 (&a)[4][2]) {
        #pragma unroll
        for (int i = 0; i < 4; ++i) {
            const int row = wr + mh * 64 + i * 16 + l15;
            #pragma unroll
            for (int kc = 0; kc < 2; ++kc) {
                const int kb = kc * 64 + lk * 16;
                a[i][kc] = *reinterpret_cast<const short8*>(
                    &As[buf][row * 128 + (kb ^ ((row & 7) << 4))]);
            }
        }
    };
    // B fragments straight from fp32 w[k][n]: lane l15 -> 16 consecutive n (64B
    // coalesced); 8 k per lane at stride OUT_DIM (scalar dword loads, L2/L3-hit).
    auto issueB = [&](int np, int k0, float (&bf)[2][2][8]) {
        const float* base = Wb + (size_t)k0 * OUT_DIM + wc + np * 32 + l15;
        #pragma unroll
        for (int nn = 0; nn < 2; ++nn)
            #pragma unroll
            for (int kc = 0; kc < 2; ++kc)
                #pragma unroll
                for (int kk = 0; kk < 8; ++kk)
                    bf[nn][kc][kk] = base[(size_t)(kc * 32 + lk * 8 + kk) * OUT_DIM + nn * 16];
    };
    auto cvtB = [&](float (&bf)[2][2][8], short8 (&b)[2][2]) {
        #pragma unroll
        for (int nn = 0; nn < 2; ++nn)
            #pragma unroll
            for (int kc = 0; kc < 2; ++kc) {
                short8 t;
                #pragma unroll
                for (int kk = 0; kk < 8; ++kk) t[kk] = (short)f2bf(bf[nn][kc][kk]);
                b[nn][kc] = t;
            }
    };
    auto qmfma = [&](short8 (&a)[4][2], short8 (&b)[2][2], int mh, int np) {
        __builtin_amdgcn_s_setprio(1);
        #pragma unroll
        for (int i = 0; i < 4; ++i)
            #pragma unroll
            for (int nn = 0; nn < 2; ++nn)
                #pragma unroll
                for (int kc = 0; kc < 2; ++kc)
                    acc[mh * 4 + i][np * 2 + nn] = __builtin_amdgcn_mfma_f32_16x16x32_bf16(
                        a[i][kc], b[nn][kc], acc[mh * 4 + i][np * 2 + nn], 0, 0, 0);
        __builtin_amdgcn_s_setprio(0);
    };

    float b0f[2][2][8], b1f[2][2][8];
    short8 b0[2][2], b1[2][2], a0[4][2], a1[4][2];

    // prologue: b0f(0) first, then A(0), A(1); wait A(0) landed (drains b0f too)
    issueB(0, 0, b0f);
    stageA(0, 0, 0); stageA(0, 0, 1);
    stageA(1, BK, 0); stageA(1, BK, 1);
    asm volatile("s_waitcnt vmcnt(4)" ::: "memory");
    __builtin_amdgcn_sched_barrier(0);
    __builtin_amdgcn_s_barrier();

    #pragma unroll 1
    for (int j = 0; j < NT; ++j) {
        const int rb = j & 1;

        // ---- ph0: quadrant (mh0,np0) ----
        readA(rb, 0, a0);
        cvtB(b0f, b0);                       // auto-wait on b0f(j)
        __builtin_amdgcn_sched_barrier(0);   // b0f dead before b1f issues
        issueB(1, j * BK, b1f);              // b1 of THIS tile (1-phase lead)
        __builtin_amdgcn_sched_barrier(0);
        qmfma(a0, b0, 0, 0);

        // ---- ph1: quadrant (mh0,np1) ----
        cvtB(b1f, b1);                       // auto-wait; drains stageA(j+1) too
        qmfma(a0, b1, 0, 1);

        // ---- ph2: quadrant (mh1,np1) ----
        readA(rb, 1, a1);
        qmfma(a1, b1, 1, 1);
        __builtin_amdgcn_sched_barrier(0);
        __builtin_amdgcn_s_barrier();        // B1: all reads of As[rb] retired

        // ---- ph3: quadrant (mh1,np0); prefetch next B + next-next A ----
        if (j + 1 < NT) issueB(0, (j + 1) * BK, b0f);
        if (j + 2 < NT) { stageA(rb, (j + 2) * BK, 0); stageA(rb, (j + 2) * BK, 1); }
        __builtin_amdgcn_sched_barrier(0);
        qmfma(a1, b0, 1, 0);
        __builtin_amdgcn_s_barrier();        // B2: tile boundary
    }

    // ---- epilogue: D layout col=lane&15, row=(lane>>4)*4+reg ----
    float* obase = out + ((size_t)bz * S_DIM + bm0 + wr) * OUT_DIM + bn0 + wc;
    #pragma unroll
    for (int m = 0; m < 8; ++m) {
        #pragma unroll
        for (int n = 0; n < 4; ++n) {
            const int col = n * 16 + l15;
            #pragma unroll
            for (int r = 0; r < 4; ++r) {
                obase[(size_t)(m * 16 + lk * 4 + r) * OUT_DIM + col] = acc[m][n][r];
            }
        }
    }
}

// ---- fallback: round-2 fused kernel (passes @1316us, needs no ws) -----------
constexpr int TMf = 128, TNf = 128, TKf = 64;
__global__ __launch_bounds__(256, 2)
void mlora_gemm(const float* __restrict__ x, const int* __restrict__ aids,
                const float* __restrict__ w, float* __restrict__ out) {
    __shared__ __align__(16) unsigned char Asf[TMf * TKf * 2];
    __shared__ __align__(16) unsigned char Bsf[TNf * TKf * 2];

    const int tid  = threadIdx.x;
    const int lane = tid & 63;
    const int wid  = tid >> 6;
    const int bn0  = blockIdx.x * TNf;
    const int bm0  = blockIdx.y * TMf;
    const int bb   = blockIdx.z;
    const int aid  = aids[bb];

    const float* Abase = x + ((size_t)bb * S_DIM + bm0) * IN_DIM;
    const float* Bbase = w + (size_t)aid * IN_DIM * OUT_DIM + bn0;

    const int wr = (wid >> 1) * 64;
    const int wc = (wid & 1) * 64;

    f32x4 acc[4][4] = {};

    const int a_row4 = tid >> 4;
    const int a_k    = (tid & 15) * 4;
    const int b_n  = tid & 127;
    const int b_k0 = (tid >> 7) * 8;
    const int l15 = lane & 15;
    const int lk  = lane >> 4;

    for (int k0 = 0; k0 < IN_DIM; k0 += TKf) {
        #pragma unroll
        for (int p = 0; p < 8; ++p) {
            const int row = p * 16 + a_row4;
            f32x4 v = *reinterpret_cast<const f32x4*>(Abase + (size_t)row * IN_DIM + (k0 + a_k));
            uint2 d;
            d.x = bf2pk(v[0], v[1]);
            d.y = bf2pk(v[2], v[3]);
            const int off = row * (TKf * 2) + ((a_k * 2) ^ ((row & 7) << 4));
            *reinterpret_cast<uint2*>(&Asf[off]) = d;
        }
        {
            const float* bp = Bbase + (size_t)(k0 + b_k0) * OUT_DIM + b_n;
            #pragma unroll
            for (int g = 0; g < 4; ++g) {
                float f0 = bp[(size_t)(g * 16 + 0) * OUT_DIM];
                float f1 = bp[(size_t)(g * 16 + 1) * OUT_DIM];
                float f2 = bp[(size_t)(g * 16 + 2) * OUT_DIM];
                float f3 = bp[(size_t)(g * 16 + 3) * OUT_DIM];
                float f4 = bp[(size_t)(g * 16 + 4) * OUT_DIM];
                float f5 = bp[(size_t)(g * 16 + 5) * OUT_DIM];
                float f6 = bp[(size_t)(g * 16 + 6) * OUT_DIM];
                float f7 = bp[(size_t)(g * 16 + 7) * OUT_DIM];
                uint4 d;
                d.x = bf2pk(f0, f1);
                d.y = bf2pk(f2, f3);
                d.z = bf2pk(f4, f5);
                d.w = bf2pk(f6, f7);
                const int ks = b_k0 + g * 16;
                const int off = b_n * (TKf * 2) + ((ks * 2) ^ ((b_n & 7) << 4));
                *reinterpret_cast<uint4*>(&Bsf[off]) = d;
            }
        }
        __syncthreads();
        #pragma unroll
        for (int kc = 0; kc < 2; ++kc) {
            const int kbyte = kc * 64 + lk * 16;
            short8 af[4], bfr[4];
            #pragma unroll
            for (int m = 0; m < 4; ++m) {
                const int row = wr + m * 16 + l15;
                af[m] = *reinterpret_cast<const short8*>(&Asf[row * (TKf * 2) + (kbyte ^ ((row & 7) << 4))]);
            }
            #pragma unroll
            for (int n = 0; n < 4; ++n) {
                const int row = wc + n * 16 + l15;
                bfr[n] = *reinterpret_cast<const short8*>(&Bsf[row * (TKf * 2) + (kbyte ^ ((row & 7) << 4))]);
            }
            #pragma unroll
            for (int m = 0; m < 4; ++m) {
                #pragma unroll
                for (int n = 0; n < 4; ++n) {
                    acc[m][n] = __builtin_amdgcn_mfma_f32_16x16x32_bf16(af[m], bfr[n], acc[m][n], 0, 0, 0);
                }
            }
        }
        __syncthreads();
    }

    float* obase = out + ((size_t)bb * S_DIM + bm0 + wr) * OUT_DIM + bn0 + wc;
    #pragma unroll
    for (int m = 0; m < 4; ++m) {
        #pragma unroll
        for (int n = 0; n < 4; ++n) {
            const int col = n * 16 + l15;
            #pragma unroll
            for (int r = 0; r < 4; ++r) {
                obase[(size_t)(m * 16 + lk * 4 + r) * OUT_DIM + col] = acc[m][n][r];
            }
        }
    }
}

extern "C" void kernel_launch(void* const* d_in, const int* in_sizes, int n_in,
                              void* d_out, int out_size, void* d_ws, size_t ws_size,
                              hipStream_t stream) {
    const float* x    = (const float*)d_in[0];
    const int*   aids = (const int*)d_in[1];
    const float* w    = (const float*)d_in[2];
    float* out = (float*)d_out;
    const int nb = in_sizes[1];  // 8

    const size_t XB_BYTES = (size_t)nb * S_DIM * IN_DIM * 2;   // 64 MiB

    if (ws_size >= XB_BYTES) {
        unsigned short* xbuf = (unsigned short*)d_ws;

        const int n8 = nb * S_DIM * IN_DIM / 8;
        prep_x<<<4096, 256, 0, stream>>>(x, xbuf, n8);

        const int nwg = nb * (S_DIM / BM) * (OUT_DIM / BN);  // 512
        gemm_f<<<nwg, 512, 0, stream>>>(xbuf, w, aids, out);
    } else {
        dim3 grid(OUT_DIM / TNf, S_DIM / TMf, nb);
        mlora_gemm<<<grid, 256, 0, stream>>>(x, aids, w, out);
    }
}

// Round 9
// 524.119 us; speedup vs baseline: 1.5000x; 1.5000x over previous
//
#include <hip/hip_runtime.h>
#include <hip/hip_bf16.h>

typedef __attribute__((ext_vector_type(8))) short short8;
typedef __attribute__((ext_vector_type(4))) float f32x4;

constexpr int S_DIM   = 1024;
constexpr int IN_DIM  = 4096;   // K
constexpr int OUT_DIM = 4096;   // N
constexpr int NLORA   = 8;

typedef __attribute__((address_space(3))) unsigned char lds_byte_t;
typedef const __attribute__((address_space(1))) unsigned char glb_byte_t;

__device__ __forceinline__ unsigned short f2bf(float a) {
    union { __hip_bfloat16 h; unsigned short u; } c;
    c.h = __float2bfloat16(a);
    return c.u;
}
__device__ __forceinline__ unsigned int bf2pk(float a, float b) {
    return (unsigned int)f2bf(a) | ((unsigned int)f2bf(b) << 16);
}

// ---- prep 1: w[a][k][n] fp32 -> wt[a][n][k] bf16, only for USED adapters ----
__global__ __launch_bounds__(256)
void prep_w(const float* __restrict__ w, unsigned short* __restrict__ wt,
            const int* __restrict__ aids, int nb) {
    const int a = blockIdx.z;
    bool used = false;
    for (int i = 0; i < nb; ++i) used |= (aids[i] == a);
    if (!used) return;

    __shared__ __align__(16) unsigned short t[64][72];
    const int tid = threadIdx.x;
    const int n0 = blockIdx.x * 64;
    const int k0 = blockIdx.y * 64;
    const float* wb = w + (size_t)a * IN_DIM * OUT_DIM;

    const int nl = (tid & 15) * 4;
    #pragma unroll
    for (int p = 0; p < 4; ++p) {
        const int kl = p * 16 + (tid >> 4);
        f32x4 v = *reinterpret_cast<const f32x4*>(wb + (size_t)(k0 + kl) * OUT_DIM + n0 + nl);
        t[nl + 0][kl] = f2bf(v[0]);
        t[nl + 1][kl] = f2bf(v[1]);
        t[nl + 2][kl] = f2bf(v[2]);
        t[nl + 3][kl] = f2bf(v[3]);
    }
    __syncthreads();
    unsigned short* wtb = wt + (size_t)a * IN_DIM * OUT_DIM;
    const int chunk = tid & 7;
    #pragma unroll
    for (int q = 0; q < 2; ++q) {
        const int row = q * 32 + (tid >> 3);
        uint4 d = *reinterpret_cast<const uint4*>(&t[row][chunk * 8]);
        *reinterpret_cast<uint4*>(wtb + (size_t)(n0 + row) * IN_DIM + k0 + chunk * 8) = d;
    }
}

// ---- prep 2: x fp32 -> bf16 -------------------------------------------------
__global__ __launch_bounds__(256)
void prep_x(const float* __restrict__ x, unsigned short* __restrict__ xb, int n8) {
    const int stride = gridDim.x * blockDim.x;
    for (int i = blockIdx.x * blockDim.x + threadIdx.x; i < n8; i += stride) {
        const size_t o = (size_t)i * 8;
        f32x4 v0 = *reinterpret_cast<const f32x4*>(x + o);
        f32x4 v1 = *reinterpret_cast<const f32x4*>(x + o + 4);
        uint4 d;
        d.x = bf2pk(v0[0], v0[1]);
        d.y = bf2pk(v0[2], v0[3]);
        d.z = bf2pk(v1[0], v1[1]);
        d.w = bf2pk(v1[2], v1[3]);
        *reinterpret_cast<uint4*>(xb + o) = d;
    }
}

// ---- main GEMM: 256x256, A via LDS (proven), B in regs from bf16 wt ---------
constexpr int BM = 256;
constexpr int BN = 256;
constexpr int BK = 64;
constexpr int NT = IN_DIM / BK;   // 64

__global__ __launch_bounds__(512, 2)
void gemm_r(const unsigned short* __restrict__ xb, const unsigned short* __restrict__ wt,
            const int* __restrict__ aids, float* __restrict__ out) {
    __shared__ __align__(16) unsigned char As[2][32768];   // A only: 64 KiB

    // T1 XCD swizzle: 512 wgs, 64/XCD = one batch per XCD
    const int bid = blockIdx.x;
    const int swz = (bid & 7) * 64 + (bid >> 3);
    const int bz  = swz >> 6;
    const int rem = swz & 63;
    const int by  = rem >> 4;
    const int bx  = rem & 15;

    const int tid  = threadIdx.x;
    const int lane = tid & 63;
    const int wid  = tid >> 6;
    const int bm0  = by * BM;
    const int bn0  = bx * BN;
    const int aid  = aids[bz];

    const unsigned short* Ab = xb + ((size_t)bz * S_DIM + bm0) * IN_DIM;

    const int wr  = (wid >> 2) * 128;
    const int wc  = (wid & 3) * 64;
    const int l15 = lane & 15;
    const int lk  = lane >> 4;

    // per-lane B base: row n = bn0 + wc + l15 (+np*32+nn*16), 16B contiguous in k
    const unsigned short* WtL = wt + (size_t)aid * IN_DIM * OUT_DIM
                                   + (size_t)(bn0 + wc + l15) * IN_DIM;

    // A staging (verified rounds 3-5): chunk = 8 rows x 128B, linear LDS dest,
    // source k pre-swizzled so ds_read with byte ^ ((row&7)<<4) is conflict-free.
    const int rl   = lane >> 3;
    const int ksrc = ((lane & 7) ^ rl) << 3;

    f32x4 acc[8][4] = {};

    // stage-group g = chunks {g*8+wid, 16+g*8+wid} = rows {g*64..+63} u {128+g*64..+63}
    // == EXACTLY the rows all 8 waves read at phase g (readA(mh=g): wr + g*64 + 0..63,
    // wr in {0,128}).  (Round-7 bug: halves 0-127/128-255 didn't match phase reads.)
    auto stageA = [&](int buf, int k0, int g) {
        #pragma unroll
        for (int c = 0; c < 2; ++c) {
            const int chunk = c * 16 + g * 8 + wid;
            const int row   = chunk * 8 + rl;
            __builtin_amdgcn_global_load_lds(
                (glb_byte_t*)(Ab + (size_t)row * IN_DIM + k0 + ksrc),
                (lds_byte_t*)(&As[buf][chunk * 1024]), 16, 0, 0);
        }
    };
    auto readA = [&](int buf, int mh, short8 (&a)[4][2]) {
        #pragma unroll
        for (int i = 0; i < 4; ++i) {
            const int row = wr + mh * 64 + i * 16 + l15;
            #pragma unroll
            for (int kc = 0; kc < 2; ++kc) {
                const int kb = kc * 64 + lk * 16;
                a[i][kc] = *reinterpret_cast<const short8*>(
                    &As[buf][row * 128 + (kb ^ ((row & 7) << 4))]);
            }
        }
    };
    // 8 x global_load_dwordx4: 16B/lane contiguous; 16 rows x 64B per instr
    auto issueB = [&](int jk, short8 (&b)[2][2][2]) {
        #pragma unroll
        for (int np = 0; np < 2; ++np)
            #pragma unroll
            for (int nn = 0; nn < 2; ++nn)
                #pragma unroll
                for (int kc = 0; kc < 2; ++kc)
                    b[np][nn][kc] = *reinterpret_cast<const short8*>(
                        WtL + (size_t)(np * 32 + nn * 16) * IN_DIM + jk + kc * 32 + lk * 8);
    };
    auto qmfma = [&](short8 (&a)[4][2], short8 (&b)[2][2], int mh, int np) {
        #pragma unroll
        for (int i = 0; i < 4; ++i)
            #pragma unroll
            for (int nn = 0; nn < 2; ++nn)
                #pragma unroll
                for (int kc = 0; kc < 2; ++kc)
                    acc[mh * 4 + i][np * 2 + nn] = __builtin_amdgcn_mfma_f32_16x16x32_bf16(
                        a[i][kc], b[nn][kc], acc[mh * 4 + i][np * 2 + nn], 0, 0, 0);
    };

    short8 bA[2][2][2], bB[2][2][2];

    // prologue: ALL A loads first (A0, A1), then B(0); vmcnt(8) drains the 8 A
    // loads (covers tiles 0 AND 1); B(0) waited via register deps at tile 0 ph0.
    stageA(0, 0, 0); stageA(0, 0, 1);
    stageA(1, BK, 0); stageA(1, BK, 1);
    issueB(0, bA);
    asm volatile("s_waitcnt vmcnt(8)" ::: "memory");
    __builtin_amdgcn_sched_barrier(0);
    __builtin_amdgcn_s_barrier();

    // FIFO order pinned by sched_barrier(0) after each stage:
    //   stage(g0,j+2) < issueB(j+1) < stage(g1,j+2) < issueB(j+2)
    // -> compiler's vmcnt wait on bcur before tile j+1 ph0 MFMAs drains
    //    stage(g0,j+2) one full tile before its read at tile j+2 ph0;
    //    the wait on issueB(j+2) (tile j+2 ph0) drains stage(g1,j+2) before
    //    its read at tile j+2 ph1.  Never drains to 0 in steady state.
    auto tile_body = [&](int j, short8 (&bcur)[2][2][2], short8 (&bnext)[2][2][2]) {
        const int rb = j & 1;
        short8 a[4][2];

        // ---- ph0: rows wr..wr+63 (= stage-group 0) ----
        readA(rb, 0, a);
        __builtin_amdgcn_sched_barrier(0);
        __builtin_amdgcn_s_setprio(1);
        qmfma(a, bcur[0], 0, 0);
        qmfma(a, bcur[1], 0, 1);
        __builtin_amdgcn_s_setprio(0);
        __builtin_amdgcn_sched_barrier(0);
        __builtin_amdgcn_s_barrier();          // all ph0 reads (group0 rows) retired
        if (j + 2 < NT) stageA(rb, (j + 2) * BK, 0);
        __builtin_amdgcn_sched_barrier(0);

        // ---- ph1: rows wr+64..wr+127 (= stage-group 1) ----
        readA(rb, 1, a);
        if (j + 1 < NT) issueB((j + 1) * BK, bnext);
        __builtin_amdgcn_sched_barrier(0);
        __builtin_amdgcn_s_setprio(1);
        qmfma(a, bcur[0], 1, 0);
        qmfma(a, bcur[1], 1, 1);
        __builtin_amdgcn_s_setprio(0);
        __builtin_amdgcn_sched_barrier(0);
        __builtin_amdgcn_s_barrier();          // all ph1 reads (group1 rows) retired
        if (j + 2 < NT) stageA(rb, (j + 2) * BK, 1);
        __builtin_amdgcn_sched_barrier(0);
    };

    #pragma unroll 1
    for (int j = 0; j < NT; j += 2) {
        tile_body(j, bA, bB);
        tile_body(j + 1, bB, bA);
    }

    // ---- epilogue: D layout col=lane&15, row=(lane>>4)*4+reg ----
    float* obase = out + ((size_t)bz * S_DIM + bm0 + wr) * OUT_DIM + bn0 + wc;
    #pragma unroll
    for (int m = 0; m < 8; ++m) {
        #pragma unroll
        for (int n = 0; n < 4; ++n) {
            const int col = n * 16 + l15;
            #pragma unroll
            for (int r = 0; r < 4; ++r) {
                obase[(size_t)(m * 16 + lk * 4 + r) * OUT_DIM + col] = acc[m][n][r];
            }
        }
    }
}

// ---- fallback: round-2 fused kernel (passes @1316us, needs no ws) -----------
constexpr int TMf = 128, TNf = 128, TKf = 64;
__global__ __launch_bounds__(256, 2)
void mlora_gemm(const float* __restrict__ x, const int* __restrict__ aids,
                const float* __restrict__ w, float* __restrict__ out) {
    __shared__ __align__(16) unsigned char Asf[TMf * TKf * 2];
    __shared__ __align__(16) unsigned char Bsf[TNf * TKf * 2];

    const int tid  = threadIdx.x;
    const int lane = tid & 63;
    const int wid  = tid >> 6;
    const int bn0  = blockIdx.x * TNf;
    const int bm0  = blockIdx.y * TMf;
    const int bb   = blockIdx.z;
    const int aid  = aids[bb];

    const float* Abase = x + ((size_t)bb * S_DIM + bm0) * IN_DIM;
    const float* Bbase = w + (size_t)aid * IN_DIM * OUT_DIM + bn0;

    const int wr = (wid >> 1) * 64;
    const int wc = (wid & 1) * 64;

    f32x4 acc[4][4] = {};

    const int a_row4 = tid >> 4;
    const int a_k    = (tid & 15) * 4;
    const int b_n  = tid & 127;
    const int b_k0 = (tid >> 7) * 8;
    const int l15 = lane & 15;
    const int lk  = lane >> 4;

    for (int k0 = 0; k0 < IN_DIM; k0 += TKf) {
        #pragma unroll
        for (int p = 0; p < 8; ++p) {
            const int row = p * 16 + a_row4;
            f32x4 v = *reinterpret_cast<const f32x4*>(Abase + (size_t)row * IN_DIM + (k0 + a_k));
            uint2 d;
            d.x = bf2pk(v[0], v[1]);
            d.y = bf2pk(v[2], v[3]);
            const int off = row * (TKf * 2) + ((a_k * 2) ^ ((row & 7) << 4));
            *reinterpret_cast<uint2*>(&Asf[off]) = d;
        }
        {
            const float* bp = Bbase + (size_t)(k0 + b_k0) * OUT_DIM + b_n;
            #pragma unroll
            for (int g = 0; g < 4; ++g) {
                float f0 = bp[(size_t)(g * 16 + 0) * OUT_DIM];
                float f1 = bp[(size_t)(g * 16 + 1) * OUT_DIM];
                float f2 = bp[(size_t)(g * 16 + 2) * OUT_DIM];
                float f3 = bp[(size_t)(g * 16 + 3) * OUT_DIM];
                float f4 = bp[(size_t)(g * 16 + 4) * OUT_DIM];
                float f5 = bp[(size_t)(g * 16 + 5) * OUT_DIM];
                float f6 = bp[(size_t)(g * 16 + 6) * OUT_DIM];
                float f7 = bp[(size_t)(g * 16 + 7) * OUT_DIM];
                uint4 d;
                d.x = bf2pk(f0, f1);
                d.y = bf2pk(f2, f3);
                d.z = bf2pk(f4, f5);
                d.w = bf2pk(f6, f7);
                const int ks = b_k0 + g * 16;
                const int off = b_n * (TKf * 2) + ((ks * 2) ^ ((b_n & 7) << 4));
                *reinterpret_cast<uint4*>(&Bsf[off]) = d;
            }
        }
        __syncthreads();
        #pragma unroll
        for (int kc = 0; kc < 2; ++kc) {
            const int kbyte = kc * 64 + lk * 16;
            short8 af[4], bfr[4];
            #pragma unroll
            for (int m = 0; m < 4; ++m) {
                const int row = wr + m * 16 + l15;
                af[m] = *reinterpret_cast<const short8*>(&Asf[row * (TKf * 2) + (kbyte ^ ((row & 7) << 4))]);
            }
            #pragma unroll
            for (int n = 0; n < 4; ++n) {
                const int row = wc + n * 16 + l15;
                bfr[n] = *reinterpret_cast<const short8*>(&Bsf[row * (TKf * 2) + (kbyte ^ ((row & 7) << 4))]);
            }
            #pragma unroll
            for (int m = 0; m < 4; ++m) {
                #pragma unroll
                for (int n = 0; n < 4; ++n) {
                    acc[m][n] = __builtin_amdgcn_mfma_f32_16x16x32_bf16(af[m], bfr[n], acc[m][n], 0, 0, 0);
                }
            }
        }
        __syncthreads();
    }

    float* obase = out + ((size_t)bb * S_DIM + bm0 + wr) * OUT_DIM + bn0 + wc;
    #pragma unroll
    for (int m = 0; m < 4; ++m) {
        #pragma unroll
        for (int n = 0; n < 4; ++n) {
            const int col = n * 16 + l15;
            #pragma unroll
            for (int r = 0; r < 4; ++r) {
                obase[(size_t)(m * 16 + lk * 4 + r) * OUT_DIM + col] = acc[m][n][r];
            }
        }
    }
}

extern "C" void kernel_launch(void* const* d_in, const int* in_sizes, int n_in,
                              void* d_out, int out_size, void* d_ws, size_t ws_size,
                              hipStream_t stream) {
    const float* x    = (const float*)d_in[0];
    const int*   aids = (const int*)d_in[1];
    const float* w    = (const float*)d_in[2];
    float* out = (float*)d_out;
    const int nb = in_sizes[1];  // 8

    const size_t WT_BYTES = (size_t)NLORA * IN_DIM * OUT_DIM * 2;   // 256 MiB
    const size_t XB_BYTES = (size_t)nb * S_DIM * IN_DIM * 2;        // 64 MiB

    if (ws_size >= WT_BYTES + XB_BYTES) {
        unsigned short* wt = (unsigned short*)d_ws;
        unsigned short* xbuf = (unsigned short*)((char*)d_ws + WT_BYTES);

        dim3 gw(OUT_DIM / 64, IN_DIM / 64, NLORA);
        prep_w<<<gw, 256, 0, stream>>>(w, wt, aids, nb);

        const int n8 = nb * S_DIM * IN_DIM / 8;
        prep_x<<<4096, 256, 0, stream>>>(x, xbuf, n8);

        const int nwg = nb * (S_DIM / BM) * (OUT_DIM / BN);  // 512
        gemm_r<<<nwg, 512, 0, stream>>>(xbuf, wt, aids, out);
    } else {
        dim3 grid(OUT_DIM / TNf, S_DIM / TMf, nb);
        mlora_gemm<<<grid, 256, 0, stream>>>(x, aids, w, out);
    }
}

// Round 10
// 360.874 us; speedup vs baseline: 2.1786x; 1.4524x over previous
//
#include <hip/hip_runtime.h>
#include <hip/hip_bf16.h>

typedef __attribute__((ext_vector_type(8))) short short8;
typedef __attribute__((ext_vector_type(4))) float f32x4;

constexpr int S_DIM   = 1024;
constexpr int IN_DIM  = 4096;   // K
constexpr int OUT_DIM = 4096;   // N
constexpr int NLORA   = 8;

typedef __attribute__((address_space(3))) unsigned char lds_byte_t;
typedef const __attribute__((address_space(1))) unsigned char glb_byte_t;

__device__ __forceinline__ unsigned short f2bf(float a) {
    union { __hip_bfloat16 h; unsigned short u; } c;
    c.h = __float2bfloat16(a);
    return c.u;
}
__device__ __forceinline__ unsigned int bf2pk(float a, float b) {
    return (unsigned int)f2bf(a) | ((unsigned int)f2bf(b) << 16);
}

// ---- fused prep: w-transpose blocks + x-convert blocks in ONE launch --------
// bid < 32768: w[a][k][n] fp32 -> wt[a][n][k] bf16 (64x64 tile; skip unused a)
// bid >= 32768: x fp32 -> bf16 grid-stride (2048 blocks)
constexpr int WBLKS = NLORA * 64 * 64;   // 32768
constexpr int XBLKS = 2048;

__global__ __launch_bounds__(256)
void prep_all(const float* __restrict__ w, unsigned short* __restrict__ wt,
              const float* __restrict__ x, unsigned short* __restrict__ xb,
              const int* __restrict__ aids, int nb, int n8) {
    const int bid = blockIdx.x;
    const int tid = threadIdx.x;

    if (bid >= WBLKS) {
        // ---- x convert ----
        const int xb0 = bid - WBLKS;
        const int stride = XBLKS * 256;
        for (int i = xb0 * 256 + tid; i < n8; i += stride) {
            const size_t o = (size_t)i * 8;
            f32x4 v0 = *reinterpret_cast<const f32x4*>(x + o);
            f32x4 v1 = *reinterpret_cast<const f32x4*>(x + o + 4);
            uint4 d;
            d.x = bf2pk(v0[0], v0[1]);
            d.y = bf2pk(v0[2], v0[3]);
            d.z = bf2pk(v1[0], v1[1]);
            d.w = bf2pk(v1[2], v1[3]);
            *reinterpret_cast<uint4*>(xb + o) = d;
        }
        return;
    }

    // ---- w transpose+convert ----
    const int a = bid >> 12;            // 4096 tiles per adapter
    bool used = false;
    for (int i = 0; i < nb; ++i) used |= (aids[i] == a);
    if (!used) return;

    const int r  = bid & 4095;
    const int n0 = (r & 63) * 64;
    const int k0 = (r >> 6) * 64;

    __shared__ __align__(16) unsigned short t[64][72];
    const float* wb = w + (size_t)a * IN_DIM * OUT_DIM;

    const int nl = (tid & 15) * 4;
    #pragma unroll
    for (int p = 0; p < 4; ++p) {
        const int kl = p * 16 + (tid >> 4);
        f32x4 v = *reinterpret_cast<const f32x4*>(wb + (size_t)(k0 + kl) * OUT_DIM + n0 + nl);
        t[nl + 0][kl] = f2bf(v[0]);
        t[nl + 1][kl] = f2bf(v[1]);
        t[nl + 2][kl] = f2bf(v[2]);
        t[nl + 3][kl] = f2bf(v[3]);
    }
    __syncthreads();
    unsigned short* wtb = wt + (size_t)a * IN_DIM * OUT_DIM;
    const int chunk = tid & 7;
    #pragma unroll
    for (int q = 0; q < 2; ++q) {
        const int row = q * 32 + (tid >> 3);
        uint4 d = *reinterpret_cast<const uint4*>(&t[row][chunk * 8]);
        *reinterpret_cast<uint4*>(wtb + (size_t)(n0 + row) * IN_DIM + k0 + chunk * 8) = d;
    }
}

// ---- main GEMM (round-5 gemm8p, verbatim): 256x256, 4 quadrant-phases/K-tile,
// counted vmcnt, lookahead-2 staging into the read buffer -----------
constexpr int BM = 256;
constexpr int BN = 256;
constexpr int BK = 64;
constexpr int NT = IN_DIM / BK;   // 64

__global__ __launch_bounds__(512, 2)
void gemm8p(const unsigned short* __restrict__ xb, const unsigned short* __restrict__ wt,
            const int* __restrict__ aids, float* __restrict__ out) {
    // 2 buffers x (A 32KiB + B 32KiB) = 128 KiB
    __shared__ __align__(16) unsigned char lds[2][65536];

    // T1 XCD swizzle: 512 wgs, 64/XCD = exactly one batch per XCD
    const int bid = blockIdx.x;
    const int swz = (bid & 7) * 64 + (bid >> 3);
    const int bz  = swz >> 6;          // batch 0..7
    const int rem = swz & 63;
    const int by  = rem >> 4;          // m-tile 0..3
    const int bx  = rem & 15;          // n-tile 0..15

    const int tid  = threadIdx.x;
    const int lane = tid & 63;
    const int wid  = tid >> 6;         // 0..7
    const int bm0  = by * BM;
    const int bn0  = bx * BN;
    const int aid  = aids[bz];

    const unsigned short* Ab = xb + ((size_t)bz * S_DIM + bm0) * IN_DIM;
    const unsigned short* Bb = wt + (size_t)aid * IN_DIM * OUT_DIM + (size_t)bn0 * IN_DIM;

    // 8 waves: 2M x 4N -> per-wave 128x64 output
    const int wr  = (wid >> 2) * 128;
    const int wc  = (wid & 3) * 64;
    const int l15 = lane & 15;
    const int lk  = lane >> 4;

    // staging: chunk = 8 rows x 128B (1 KiB), lane l -> row chunk*8 + (l>>3),
    // source k pre-swizzled so ds_read with byte ^ ((row&7)<<4) is conflict-free
    const int rl   = lane >> 3;
    const int ksrc = ((lane & 7) ^ rl) << 3;     // elements

    f32x4 acc[8][4] = {};

    auto stageA = [&](int buf, int k0, int h) {
        #pragma unroll
        for (int c = 0; c < 2; ++c) {
            const int chunk = h * 16 + wid * 2 + c;
            const int row   = chunk * 8 + rl;
            __builtin_amdgcn_global_load_lds(
                (glb_byte_t*)(Ab + (size_t)row * IN_DIM + k0 + ksrc),
                (lds_byte_t*)(&lds[buf][chunk * 1024]), 16, 0, 0);
        }
    };
    auto stageB = [&](int buf, int k0, int h) {
        #pragma unroll
        for (int c = 0; c < 2; ++c) {
            const int chunk = h * 16 + wid * 2 + c;
            const int row   = chunk * 8 + rl;
            __builtin_amdgcn_global_load_lds(
                (glb_byte_t*)(Bb + (size_t)row * IN_DIM + k0 + ksrc),
                (lds_byte_t*)(&lds[buf][32768 + chunk * 1024]), 16, 0, 0);
        }
    };

    auto readA = [&](int buf, int mh, short8 (&af)[4][2]) {
        #pragma unroll
        for (int i = 0; i < 4; ++i) {
            const int row = wr + mh * 64 + i * 16 + l15;
            #pragma unroll
            for (int kc = 0; kc < 2; ++kc) {
                const int kb = kc * 64 + lk * 16;
                af[i][kc] = *reinterpret_cast<const short8*>(
                    &lds[buf][row * 128 + (kb ^ ((row & 7) << 4))]);
            }
        }
    };
    auto readB = [&](int buf, int np, short8 (&bf)[2][2]) {
        #pragma unroll
        for (int nn = 0; nn < 2; ++nn) {
            const int row = wc + np * 32 + nn * 16 + l15;
            #pragma unroll
            for (int kc = 0; kc < 2; ++kc) {
                const int kb = kc * 64 + lk * 16;
                bf[nn][kc] = *reinterpret_cast<const short8*>(
                    &lds[buf][32768 + row * 128 + (kb ^ ((row & 7) << 4))]);
            }
        }
    };

    auto qmfma = [&](short8 (&af)[4][2], short8 (&bf)[2][2], int mh, int np) {
        __builtin_amdgcn_s_setprio(1);
        #pragma unroll
        for (int i = 0; i < 4; ++i)
            #pragma unroll
            for (int nn = 0; nn < 2; ++nn)
                #pragma unroll
                for (int kc = 0; kc < 2; ++kc)
                    acc[mh * 4 + i][np * 2 + nn] = __builtin_amdgcn_mfma_f32_16x16x32_bf16(
                        af[i][kc], bf[nn][kc], acc[mh * 4 + i][np * 2 + nn], 0, 0, 0);
        __builtin_amdgcn_s_setprio(0);
    };

    // prologue: tile0 -> buf0, tile1 -> buf1; wait tile0 landed (8 in flight)
    stageA(0, 0, 0); stageA(0, 0, 1); stageB(0, 0, 0); stageB(0, 0, 1);
    stageA(1, BK, 0); stageA(1, BK, 1); stageB(1, BK, 0); stageB(1, BK, 1);
    asm volatile("s_waitcnt vmcnt(8)" ::: "memory");
    __builtin_amdgcn_sched_barrier(0);
    __builtin_amdgcn_s_barrier();

    short8 a0[4][2], a1[4][2], b0[2][2], b1[2][2];

    #pragma unroll 1
    for (int j = 0; j < NT; ++j) {
        const int rb = j & 1;                 // read buf; tile j+2 also lands here
        const int k2 = (j + 2) * BK;
        const bool pre = (j < NT - 2);

        // ---- ph0: quadrant (mh0, np0); reads 12 ----
        readA(rb, 0, a0);
        readB(rb, 0, b0);
        __builtin_amdgcn_s_barrier();
        qmfma(a0, b0, 0, 0);
        __builtin_amdgcn_s_barrier();

        // ---- ph1: quadrant (mh0, np1); reads 4 ----
        readB(rb, 1, b1);
        __builtin_amdgcn_s_barrier();
        qmfma(a0, b1, 0, 1);
        __builtin_amdgcn_s_barrier();
        __builtin_amdgcn_sched_barrier(0);    // all B reads of tile j drained here

        // ---- ph2: quadrant (mh1, np1); reads 8; stage B' (tile j+2) ----
        readA(rb, 1, a1);
        if (pre) { stageB(rb, k2, 0); stageB(rb, k2, 1); }
        __builtin_amdgcn_s_barrier();
        qmfma(a1, b1, 1, 1);
        __builtin_amdgcn_s_barrier();
        __builtin_amdgcn_sched_barrier(0);    // all A reads of tile j drained here

        // ---- ph3: quadrant (mh1, np0); reads 0; stage A' (tile j+2) ----
        if (pre) {
            stageA(rb, k2, 0); stageA(rb, k2, 1);
            asm volatile("s_waitcnt vmcnt(8)" ::: "memory");  // tile j+1 landed
        } else if (j == NT - 2) {
            asm volatile("s_waitcnt vmcnt(0)" ::: "memory");  // drain last tile
        }
        __builtin_amdgcn_sched_barrier(0);
        __builtin_amdgcn_s_barrier();
        qmfma(a1, b0, 1, 0);
        __builtin_amdgcn_s_barrier();
    }

    // ---- epilogue: D layout col=lane&15, row=(lane>>4)*4+reg ----
    float* obase = out + ((size_t)bz * S_DIM + bm0 + wr) * OUT_DIM + bn0 + wc;
    #pragma unroll
    for (int m = 0; m < 8; ++m) {
        #pragma unroll
        for (int n = 0; n < 4; ++n) {
            const int col = n * 16 + l15;
            #pragma unroll
            for (int r = 0; r < 4; ++r) {
                obase[(size_t)(m * 16 + lk * 4 + r) * OUT_DIM + col] = acc[m][n][r];
            }
        }
    }
}

// ---- fallback: round-2 fused kernel (passes @1316us, needs no ws) -----------
constexpr int TMf = 128, TNf = 128, TKf = 64;
__global__ __launch_bounds__(256, 2)
void mlora_gemm(const float* __restrict__ x, const int* __restrict__ aids,
                const float* __restrict__ w, float* __restrict__ out) {
    __shared__ __align__(16) unsigned char Asf[TMf * TKf * 2];
    __shared__ __align__(16) unsigned char Bsf[TNf * TKf * 2];

    const int tid  = threadIdx.x;
    const int lane = tid & 63;
    const int wid  = tid >> 6;
    const int bn0  = blockIdx.x * TNf;
    const int bm0  = blockIdx.y * TMf;
    const int bb   = blockIdx.z;
    const int aid  = aids[bb];

    const float* Abase = x + ((size_t)bb * S_DIM + bm0) * IN_DIM;
    const float* Bbase = w + (size_t)aid * IN_DIM * OUT_DIM + bn0;

    const int wr = (wid >> 1) * 64;
    const int wc = (wid & 1) * 64;

    f32x4 acc[4][4] = {};

    const int a_row4 = tid >> 4;
    const int a_k    = (tid & 15) * 4;
    const int b_n  = tid & 127;
    const int b_k0 = (tid >> 7) * 8;
    const int l15 = lane & 15;
    const int lk  = lane >> 4;

    for (int k0 = 0; k0 < IN_DIM; k0 += TKf) {
        #pragma unroll
        for (int p = 0; p < 8; ++p) {
            const int row = p * 16 + a_row4;
            f32x4 v = *reinterpret_cast<const f32x4*>(Abase + (size_t)row * IN_DIM + (k0 + a_k));
            uint2 d;
            d.x = bf2pk(v[0], v[1]);
            d.y = bf2pk(v[2], v[3]);
            const int off = row * (TKf * 2) + ((a_k * 2) ^ ((row & 7) << 4));
            *reinterpret_cast<uint2*>(&Asf[off]) = d;
        }
        {
            const float* bp = Bbase + (size_t)(k0 + b_k0) * OUT_DIM + b_n;
            #pragma unroll
            for (int g = 0; g < 4; ++g) {
                float f0 = bp[(size_t)(g * 16 + 0) * OUT_DIM];
                float f1 = bp[(size_t)(g * 16 + 1) * OUT_DIM];
                float f2 = bp[(size_t)(g * 16 + 2) * OUT_DIM];
                float f3 = bp[(size_t)(g * 16 + 3) * OUT_DIM];
                float f4 = bp[(size_t)(g * 16 + 4) * OUT_DIM];
                float f5 = bp[(size_t)(g * 16 + 5) * OUT_DIM];
                float f6 = bp[(size_t)(g * 16 + 6) * OUT_DIM];
                float f7 = bp[(size_t)(g * 16 + 7) * OUT_DIM];
                uint4 d;
                d.x = bf2pk(f0, f1);
                d.y = bf2pk(f2, f3);
                d.z = bf2pk(f4, f5);
                d.w = bf2pk(f6, f7);
                const int ks = b_k0 + g * 16;
                const int off = b_n * (TKf * 2) + ((ks * 2) ^ ((b_n & 7) << 4));
                *reinterpret_cast<uint4*>(&Bsf[off]) = d;
            }
        }
        __syncthreads();
        #pragma unroll
        for (int kc = 0; kc < 2; ++kc) {
            const int kbyte = kc * 64 + lk * 16;
            short8 af[4], bfr[4];
            #pragma unroll
            for (int m = 0; m < 4; ++m) {
                const int row = wr + m * 16 + l15;
                af[m] = *reinterpret_cast<const short8*>(&Asf[row * (TKf * 2) + (kbyte ^ ((row & 7) << 4))]);
            }
            #pragma unroll
            for (int n = 0; n < 4; ++n) {
                const int row = wc + n * 16 + l15;
                bfr[n] = *reinterpret_cast<const short8*>(&Bsf[row * (TKf * 2) + (kbyte ^ ((row & 7) << 4))]);
            }
            #pragma unroll
            for (int m = 0; m < 4; ++m) {
                #pragma unroll
                for (int n = 0; n < 4; ++n) {
                    acc[m][n] = __builtin_amdgcn_mfma_f32_16x16x32_bf16(af[m], bfr[n], acc[m][n], 0, 0, 0);
                }
            }
        }
        __syncthreads();
    }

    float* obase = out + ((size_t)bb * S_DIM + bm0 + wr) * OUT_DIM + bn0 + wc;
    #pragma unroll
    for (int m = 0; m < 4; ++m) {
        #pragma unroll
        for (int n = 0; n < 4; ++n) {
            const int col = n * 16 + l15;
            #pragma unroll
            for (int r = 0; r < 4; ++r) {
                obase[(size_t)(m * 16 + lk * 4 + r) * OUT_DIM + col] = acc[m][n][r];
            }
        }
    }
}

extern "C" void kernel_launch(void* const* d_in, const int* in_sizes, int n_in,
                              void* d_out, int out_size, void* d_ws, size_t ws_size,
                              hipStream_t stream) {
    const float* x    = (const float*)d_in[0];
    const int*   aids = (const int*)d_in[1];
    const float* w    = (const float*)d_in[2];
    float* out = (float*)d_out;
    const int nb = in_sizes[1];  // 8

    const size_t WT_BYTES = (size_t)NLORA * IN_DIM * OUT_DIM * 2;   // 256 MiB
    const size_t XB_BYTES = (size_t)nb * S_DIM * IN_DIM * 2;        // 64 MiB

    if (ws_size >= WT_BYTES + XB_BYTES) {
        unsigned short* wt = (unsigned short*)d_ws;
        unsigned short* xbuf = (unsigned short*)((char*)d_ws + WT_BYTES);

        const int n8 = nb * S_DIM * IN_DIM / 8;
        prep_all<<<WBLKS + XBLKS, 256, 0, stream>>>(w, wt, x, xbuf, aids, nb, n8);

        const int nwg = nb * (S_DIM / BM) * (OUT_DIM / BN);  // 512
        gemm8p<<<nwg, 512, 0, stream>>>(xbuf, wt, aids, out);
    } else {
        dim3 grid(OUT_DIM / TNf, S_DIM / TMf, nb);
        mlora_gemm<<<grid, 256, 0, stream>>>(x, aids, w, out);
    }
}

// Round 11
// 356.104 us; speedup vs baseline: 2.2078x; 1.0134x over previous
//
#include <hip/hip_runtime.h>
#include <hip/hip_bf16.h>

typedef __attribute__((ext_vector_type(8))) short short8;
typedef __attribute__((ext_vector_type(4))) float f32x4;

constexpr int S_DIM   = 1024;
constexpr int IN_DIM  = 4096;   // K
constexpr int OUT_DIM = 4096;   // N
constexpr int NLORA   = 8;

typedef __attribute__((address_space(3))) unsigned char lds_byte_t;
typedef const __attribute__((address_space(1))) unsigned char glb_byte_t;

__device__ __forceinline__ unsigned short f2bf(float a) {
    union { __hip_bfloat16 h; unsigned short u; } c;
    c.h = __float2bfloat16(a);
    return c.u;
}
__device__ __forceinline__ unsigned int bf2pk(float a, float b) {
    return (unsigned int)f2bf(a) | ((unsigned int)f2bf(b) << 16);
}

// ---- fused prep: w-transpose blocks + x-convert blocks in ONE launch --------
constexpr int WBLKS = NLORA * 64 * 64;   // 32768
constexpr int XBLKS = 2048;

__global__ __launch_bounds__(256)
void prep_all(const float* __restrict__ w, unsigned short* __restrict__ wt,
              const float* __restrict__ x, unsigned short* __restrict__ xb,
              const int* __restrict__ aids, int nb, int n8) {
    const int bid = blockIdx.x;
    const int tid = threadIdx.x;

    if (bid >= WBLKS) {
        const int xb0 = bid - WBLKS;
        const int stride = XBLKS * 256;
        for (int i = xb0 * 256 + tid; i < n8; i += stride) {
            const size_t o = (size_t)i * 8;
            f32x4 v0 = *reinterpret_cast<const f32x4*>(x + o);
            f32x4 v1 = *reinterpret_cast<const f32x4*>(x + o + 4);
            uint4 d;
            d.x = bf2pk(v0[0], v0[1]);
            d.y = bf2pk(v0[2], v0[3]);
            d.z = bf2pk(v1[0], v1[1]);
            d.w = bf2pk(v1[2], v1[3]);
            *reinterpret_cast<uint4*>(xb + o) = d;
        }
        return;
    }

    const int a = bid >> 12;
    bool used = false;
    for (int i = 0; i < nb; ++i) used |= (aids[i] == a);
    if (!used) return;

    const int r  = bid & 4095;
    const int n0 = (r & 63) * 64;
    const int k0 = (r >> 6) * 64;

    __shared__ __align__(16) unsigned short t[64][72];
    const float* wb = w + (size_t)a * IN_DIM * OUT_DIM;

    const int nl = (tid & 15) * 4;
    #pragma unroll
    for (int p = 0; p < 4; ++p) {
        const int kl = p * 16 + (tid >> 4);
        f32x4 v = *reinterpret_cast<const f32x4*>(wb + (size_t)(k0 + kl) * OUT_DIM + n0 + nl);
        t[nl + 0][kl] = f2bf(v[0]);
        t[nl + 1][kl] = f2bf(v[1]);
        t[nl + 2][kl] = f2bf(v[2]);
        t[nl + 3][kl] = f2bf(v[3]);
    }
    __syncthreads();
    unsigned short* wtb = wt + (size_t)a * IN_DIM * OUT_DIM;
    const int chunk = tid & 7;
    #pragma unroll
    for (int q = 0; q < 2; ++q) {
        const int row = q * 32 + (tid >> 3);
        uint4 d = *reinterpret_cast<const uint4*>(&t[row][chunk * 8]);
        *reinterpret_cast<uint4*>(wtb + (size_t)(n0 + row) * IN_DIM + k0 + chunk * 8) = d;
    }
}

// ---- main GEMM: 256x256, 4 phases/K-tile, PER-PHASE staggered staging -------
constexpr int BM = 256;
constexpr int BN = 256;
constexpr int BK = 64;
constexpr int NT = IN_DIM / BK;   // 64

__global__ __launch_bounds__(512, 2)
void gemm8p(const unsigned short* __restrict__ xb, const unsigned short* __restrict__ wt,
            const int* __restrict__ aids, float* __restrict__ out) {
    __shared__ __align__(16) unsigned char lds[2][65536];

    // T1 XCD swizzle: 512 wgs, 64/XCD = exactly one batch per XCD
    const int bid = blockIdx.x;
    const int swz = (bid & 7) * 64 + (bid >> 3);
    const int bz  = swz >> 6;
    const int rem = swz & 63;
    const int by  = rem >> 4;
    const int bx  = rem & 15;

    const int tid  = threadIdx.x;
    const int lane = tid & 63;
    const int wid  = tid >> 6;
    const int bm0  = by * BM;
    const int bn0  = bx * BN;
    const int aid  = aids[bz];

    const unsigned short* Ab = xb + ((size_t)bz * S_DIM + bm0) * IN_DIM;
    const unsigned short* Bb = wt + (size_t)aid * IN_DIM * OUT_DIM + (size_t)bn0 * IN_DIM;

    const int wr  = (wid >> 2) * 128;
    const int wc  = (wid & 3) * 64;
    const int l15 = lane & 15;
    const int lk  = lane >> 4;

    // staging: chunk = 8 rows x 128B, linear LDS dest, source k pre-swizzled
    // so ds_read with byte ^ ((row&7)<<4) is conflict-free (verified r3-r10).
    const int rl   = lane >> 3;
    const int ksrc = ((lane & 7) ^ rl) << 3;

    f32x4 acc[8][4] = {};

    // A group g (g=mh): rows {g*64..+63} u {128+g*64..+63} = chunks c*16+g*8+wid
    // == exactly the rows ALL waves read at readA(mh=g)  [proven r8/r9]
    auto stageA = [&](int buf, int k0, int g) {
        #pragma unroll
        for (int c = 0; c < 2; ++c) {
            const int chunk = c * 16 + g * 8 + wid;
            const int row   = chunk * 8 + rl;
            __builtin_amdgcn_global_load_lds(
                (glb_byte_t*)(Ab + (size_t)row * IN_DIM + k0 + ksrc),
                (lds_byte_t*)(&lds[buf][chunk * 1024]), 16, 0, 0);
        }
    };
    // B group g (g=np): rows {w*64+g*32..+31 : w=0..3} = chunks (wid>>1)*8+g*4+(wid&1)*2+c
    // == exactly the rows ALL waves read at readB(np=g)
    auto stageB = [&](int buf, int k0, int g) {
        #pragma unroll
        for (int c = 0; c < 2; ++c) {
            const int chunk = (wid >> 1) * 8 + g * 4 + (wid & 1) * 2 + c;
            const int row   = chunk * 8 + rl;
            __builtin_amdgcn_global_load_lds(
                (glb_byte_t*)(Bb + (size_t)row * IN_DIM + k0 + ksrc),
                (lds_byte_t*)(&lds[buf][32768 + chunk * 1024]), 16, 0, 0);
        }
    };

    auto readA = [&](int buf, int mh, short8 (&af)[4][2]) {
        #pragma unroll
        for (int i = 0; i < 4; ++i) {
            const int row = wr + mh * 64 + i * 16 + l15;
            #pragma unroll
            for (int kc = 0; kc < 2; ++kc) {
                const int kb = kc * 64 + lk * 16;
                af[i][kc] = *reinterpret_cast<const short8*>(
                    &lds[buf][row * 128 + (kb ^ ((row & 7) << 4))]);
            }
        }
    };
    auto readB = [&](int buf, int np, short8 (&bf)[2][2]) {
        #pragma unroll
        for (int nn = 0; nn < 2; ++nn) {
            const int row = wc + np * 32 + nn * 16 + l15;
            #pragma unroll
            for (int kc = 0; kc < 2; ++kc) {
                const int kb = kc * 64 + lk * 16;
                bf[nn][kc] = *reinterpret_cast<const short8*>(
                    &lds[buf][32768 + row * 128 + (kb ^ ((row & 7) << 4))]);
            }
        }
    };

    auto qmfma = [&](short8 (&af)[4][2], short8 (&bf)[2][2], int mh, int np) {
        __builtin_amdgcn_s_setprio(1);
        #pragma unroll
        for (int i = 0; i < 4; ++i)
            #pragma unroll
            for (int nn = 0; nn < 2; ++nn)
                #pragma unroll
                for (int kc = 0; kc < 2; ++kc)
                    acc[mh * 4 + i][np * 2 + nn] = __builtin_amdgcn_mfma_f32_16x16x32_bf16(
                        af[i][kc], bf[nn][kc], acc[mh * 4 + i][np * 2 + nn], 0, 0, 0);
        __builtin_amdgcn_s_setprio(0);
    };

    // prologue: tile0 -> buf0 (8 loads), tile1 -> buf1 (8); vmcnt(8) drains tile0
    stageA(0, 0, 0); stageA(0, 0, 1); stageB(0, 0, 0); stageB(0, 0, 1);
    stageA(1, BK, 0); stageA(1, BK, 1); stageB(1, BK, 0); stageB(1, BK, 1);
    asm volatile("s_waitcnt vmcnt(8)" ::: "memory");
    __builtin_amdgcn_sched_barrier(0);
    __builtin_amdgcn_s_barrier();

    short8 a0[4][2], a1[4][2], b0[2][2], b1[2][2];

    #pragma unroll 1
    for (int j = 0; j < NT; ++j) {
        const int rb = j & 1;                 // read buf; tile j+2 lands here too
        const int k2 = (j + 2) * BK;
        const bool pre = (j < NT - 2);

        // ---- ph0: (mh0,np0); no stage (nothing of tile j retired yet) ----
        readA(rb, 0, a0);
        readB(rb, 0, b0);
        __builtin_amdgcn_s_barrier();
        qmfma(a0, b0, 0, 0);
        __builtin_amdgcn_s_barrier();

        // ---- ph1: (mh0,np1); stage B-np0 (retired at ph0-end barrier) ----
        readB(rb, 1, b1);
        if (pre) stageB(rb, k2, 0);
        __builtin_amdgcn_sched_barrier(0);
        __builtin_amdgcn_s_barrier();
        qmfma(a0, b1, 0, 1);
        __builtin_amdgcn_s_barrier();

        // ---- ph2: (mh1,np1); stage A-mh0 (retired at ph0-end barrier) ----
        readA(rb, 1, a1);
        if (pre) stageA(rb, k2, 0);
        __builtin_amdgcn_sched_barrier(0);
        __builtin_amdgcn_s_barrier();
        qmfma(a1, b1, 1, 1);
        __builtin_amdgcn_s_barrier();

        // ---- ph3: (mh1,np0); stage B-np1 (ph1-end) + A-mh1 (ph2-end) ----
        if (pre) {
            stageB(rb, k2, 1);
            stageA(rb, k2, 1);
            asm volatile("s_waitcnt vmcnt(8)" ::: "memory");  // tile j+1 landed
        } else if (j == NT - 2) {
            asm volatile("s_waitcnt vmcnt(0)" ::: "memory");  // drain last tile
        }
        __builtin_amdgcn_sched_barrier(0);
        __builtin_amdgcn_s_barrier();
        qmfma(a1, b0, 1, 0);
        __builtin_amdgcn_s_barrier();
    }

    // ---- epilogue: D layout col=lane&15, row=(lane>>4)*4+reg ----
    float* obase = out + ((size_t)bz * S_DIM + bm0 + wr) * OUT_DIM + bn0 + wc;
    #pragma unroll
    for (int m = 0; m < 8; ++m) {
        #pragma unroll
        for (int n = 0; n < 4; ++n) {
            const int col = n * 16 + l15;
            #pragma unroll
            for (int r = 0; r < 4; ++r) {
                obase[(size_t)(m * 16 + lk * 4 + r) * OUT_DIM + col] = acc[m][n][r];
            }
        }
    }
}

// ---- fallback: round-2 fused kernel (passes @1316us, needs no ws) -----------
constexpr int TMf = 128, TNf = 128, TKf = 64;
__global__ __launch_bounds__(256, 2)
void mlora_gemm(const float* __restrict__ x, const int* __restrict__ aids,
                const float* __restrict__ w, float* __restrict__ out) {
    __shared__ __align__(16) unsigned char Asf[TMf * TKf * 2];
    __shared__ __align__(16) unsigned char Bsf[TNf * TKf * 2];

    const int tid  = threadIdx.x;
    const int lane = tid & 63;
    const int wid  = tid >> 6;
    const int bn0  = blockIdx.x * TNf;
    const int bm0  = blockIdx.y * TMf;
    const int bb   = blockIdx.z;
    const int aid  = aids[bb];

    const float* Abase = x + ((size_t)bb * S_DIM + bm0) * IN_DIM;
    const float* Bbase = w + (size_t)aid * IN_DIM * OUT_DIM + bn0;

    const int wr = (wid >> 1) * 64;
    const int wc = (wid & 1) * 64;

    f32x4 acc[4][4] = {};

    const int a_row4 = tid >> 4;
    const int a_k    = (tid & 15) * 4;
    const int b_n  = tid & 127;
    const int b_k0 = (tid >> 7) * 8;
    const int l15 = lane & 15;
    const int lk  = lane >> 4;

    for (int k0 = 0; k0 < IN_DIM; k0 += TKf) {
        #pragma unroll
        for (int p = 0; p < 8; ++p) {
            const int row = p * 16 + a_row4;
            f32x4 v = *reinterpret_cast<const f32x4*>(Abase + (size_t)row * IN_DIM + (k0 + a_k));
            uint2 d;
            d.x = bf2pk(v[0], v[1]);
            d.y = bf2pk(v[2], v[3]);
            const int off = row * (TKf * 2) + ((a_k * 2) ^ ((row & 7) << 4));
            *reinterpret_cast<uint2*>(&Asf[off]) = d;
        }
        {
            const float* bp = Bbase + (size_t)(k0 + b_k0) * OUT_DIM + b_n;
            #pragma unroll
            for (int g = 0; g < 4; ++g) {
                float f0 = bp[(size_t)(g * 16 + 0) * OUT_DIM];
                float f1 = bp[(size_t)(g * 16 + 1) * OUT_DIM];
                float f2 = bp[(size_t)(g * 16 + 2) * OUT_DIM];
                float f3 = bp[(size_t)(g * 16 + 3) * OUT_DIM];
                float f4 = bp[(size_t)(g * 16 + 4) * OUT_DIM];
                float f5 = bp[(size_t)(g * 16 + 5) * OUT_DIM];
                float f6 = bp[(size_t)(g * 16 + 6) * OUT_DIM];
                float f7 = bp[(size_t)(g * 16 + 7) * OUT_DIM];
                uint4 d;
                d.x = bf2pk(f0, f1);
                d.y = bf2pk(f2, f3);
                d.z = bf2pk(f4, f5);
                d.w = bf2pk(f6, f7);
                const int ks = b_k0 + g * 16;
                const int off = b_n * (TKf * 2) + ((ks * 2) ^ ((b_n & 7) << 4));
                *reinterpret_cast<uint4*>(&Bsf[off]) = d;
            }
        }
        __syncthreads();
        #pragma unroll
        for (int kc = 0; kc < 2; ++kc) {
            const int kbyte = kc * 64 + lk * 16;
            short8 af[4], bfr[4];
            #pragma unroll
            for (int m = 0; m < 4; ++m) {
                const int row = wr + m * 16 + l15;
                af[m] = *reinterpret_cast<const short8*>(&Asf[row * (TKf * 2) + (kbyte ^ ((row & 7) << 4))]);
            }
            #pragma unroll
            for (int n = 0; n < 4; ++n) {
                const int row = wc + n * 16 + l15;
                bfr[n] = *reinterpret_cast<const short8*>(&Bsf[row * (TKf * 2) + (kbyte ^ ((row & 7) << 4))]);
            }
            #pragma unroll
            for (int m = 0; m < 4; ++m) {
                #pragma unroll
                for (int n = 0; n < 4; ++n) {
                    acc[m][n] = __builtin_amdgcn_mfma_f32_16x16x32_bf16(af[m], bfr[n], acc[m][n], 0, 0, 0);
                }
            }
        }
        __syncthreads();
    }

    float* obase = out + ((size_t)bb * S_DIM + bm0 + wr) * OUT_DIM + bn0 + wc;
    #pragma unroll
    for (int m = 0; m < 4; ++m) {
        #pragma unroll
        for (int n = 0; n < 4; ++n) {
            const int col = n * 16 + l15;
            #pragma unroll
            for (int r = 0; r < 4; ++r) {
                obase[(size_t)(m * 16 + lk * 4 + r) * OUT_DIM + col] = acc[m][n][r];
            }
        }
    }
}

extern "C" void kernel_launch(void* const* d_in, const int* in_sizes, int n_in,
                              void* d_out, int out_size, void* d_ws, size_t ws_size,
                              hipStream_t stream) {
    const float* x    = (const float*)d_in[0];
    const int*   aids = (const int*)d_in[1];
    const float* w    = (const float*)d_in[2];
    float* out = (float*)d_out;
    const int nb = in_sizes[1];  // 8

    const size_t WT_BYTES = (size_t)NLORA * IN_DIM * OUT_DIM * 2;   // 256 MiB
    const size_t XB_BYTES = (size_t)nb * S_DIM * IN_DIM * 2;        // 64 MiB

    if (ws_size >= WT_BYTES + XB_BYTES) {
        unsigned short* wt = (unsigned short*)d_ws;
        unsigned short* xbuf = (unsigned short*)((char*)d_ws + WT_BYTES);

        const int n8 = nb * S_DIM * IN_DIM / 8;
        prep_all<<<WBLKS + XBLKS, 256, 0, stream>>>(w, wt, x, xbuf, aids, nb, n8);

        const int nwg = nb * (S_DIM / BM) * (OUT_DIM / BN);  // 512
        gemm8p<<<nwg, 512, 0, stream>>>(xbuf, wt, aids, out);
    } else {
        dim3 grid(OUT_DIM / TNf, S_DIM / TMf, nb);
        mlora_gemm<<<grid, 256, 0, stream>>>(x, aids, w, out);
    }
}